// Round 1
// baseline (56.378 us; speedup 1.0000x reference)
//
#include <hip/hip_runtime.h>

#define OUT_F 11008
#define IN_F  4096
#define BATCH 8

// ---------------- prologue: per-batch input row sums -> d_ws[0..7] ---------
__global__ void insum_kernel(const float* __restrict__ in, float* __restrict__ sums) {
    // 8 waves (512 threads), wave b sums input[b][:]
    const int wave = threadIdx.x >> 6;
    const int lane = threadIdx.x & 63;
    const float* row = in + wave * IN_F;
    float s = 0.f;
    #pragma unroll
    for (int i0 = 0; i0 < IN_F; i0 += 64 * 4) {
        float4 v = *reinterpret_cast<const float4*>(row + i0 + lane * 4);
        s += (v.x + v.y) + (v.z + v.w);
    }
    #pragma unroll
    for (int d = 1; d < 64; d <<= 1) s += __shfl_xor(s, d);
    if (lane == 0) sums[wave] = s;
}

// ---------------- main kernel: 4 rows per wave, one group per wave ---------
__global__ __launch_bounds__(256) void qlinear_kernel(
        const float* __restrict__ in, const int* __restrict__ qw,
        const int* __restrict__ zp, const float* __restrict__ scale,
        const float* __restrict__ bias, const float* __restrict__ insum,
        float* __restrict__ out) {
    const int wave  = threadIdx.x >> 6;            // 0..3
    const int lane  = threadIdx.x & 63;
    const int group = blockIdx.x * 4 + wave;       // 0..2751
    const int row0  = group * 4;                   // 4 consecutive output rows

    float acc[4][8];
    #pragma unroll
    for (int r = 0; r < 4; ++r)
        #pragma unroll
        for (int b = 0; b < 8; ++b) acc[r][b] = 0.f;

    const int* q0 = qw + (size_t)(row0 + 0) * IN_F;
    const int* q1 = qw + (size_t)(row0 + 1) * IN_F;
    const int* q2 = qw + (size_t)(row0 + 2) * IN_F;
    const int* q3 = qw + (size_t)(row0 + 3) * IN_F;

    // K loop: 16 steps; per step each lane handles 4 consecutive k (coalesced int4)
    #pragma unroll 2
    for (int step = 0; step < IN_F / 256; ++step) {
        const int i = step * 256 + lane * 4;

        int4 w0 = *reinterpret_cast<const int4*>(q0 + i);
        int4 w1 = *reinterpret_cast<const int4*>(q1 + i);
        int4 w2 = *reinterpret_cast<const int4*>(q2 + i);
        int4 w3 = *reinterpret_cast<const int4*>(q3 + i);

        float4 x[8];
        #pragma unroll
        for (int b = 0; b < 8; ++b)
            x[b] = *reinterpret_cast<const float4*>(in + b * IN_F + i);

        float f0x = (float)w0.x, f0y = (float)w0.y, f0z = (float)w0.z, f0w = (float)w0.w;
        float f1x = (float)w1.x, f1y = (float)w1.y, f1z = (float)w1.z, f1w = (float)w1.w;
        float f2x = (float)w2.x, f2y = (float)w2.y, f2z = (float)w2.z, f2w = (float)w2.w;
        float f3x = (float)w3.x, f3y = (float)w3.y, f3z = (float)w3.z, f3w = (float)w3.w;

        #pragma unroll
        for (int b = 0; b < 8; ++b) {
            acc[0][b] += f0x * x[b].x + f0y * x[b].y + f0z * x[b].z + f0w * x[b].w;
            acc[1][b] += f1x * x[b].x + f1y * x[b].y + f1z * x[b].z + f1w * x[b].w;
            acc[2][b] += f2x * x[b].x + f2y * x[b].y + f2z * x[b].z + f2w * x[b].w;
            acc[3][b] += f3x * x[b].x + f3y * x[b].y + f3z * x[b].z + f3w * x[b].w;
        }
    }

    // --- cross-lane reduce of 32 accumulators via register-halving tree ---
    // flat index idx = r*8 + b; after 5 halving levels lane l holds acc[(l&31)]
    float v[32];
    #pragma unroll
    for (int r = 0; r < 4; ++r)
        #pragma unroll
        for (int b = 0; b < 8; ++b) v[r * 8 + b] = acc[r][b];

    #pragma unroll
    for (int k = 0; k < 5; ++k) {
        const bool hi = (lane >> k) & 1;
        const int  n  = 32 >> k;
        #pragma unroll
        for (int i = 0; i < 32; ++i) {   // static bounds; only i < n/2 live
            if (i < n / 2) {
                float keep = hi ? v[2 * i + 1] : v[2 * i];
                float send = hi ? v[2 * i]     : v[2 * i + 1];
                v[i] = keep + __shfl_xor(send, 1 << k);
            }
        }
    }
    float total = v[0] + __shfl_xor(v[0], 32);   // full 64-lane sum

    if (lane < 32) {
        const int r = lane >> 3;
        const int b = lane & 7;
        const int o = row0 + r;
        const float res = scale[o] * (total - (float)zp[o] * insum[b]) + bias[o];
        out[(size_t)b * OUT_F + o] = res;
    }
}

extern "C" void kernel_launch(void* const* d_in, const int* in_sizes, int n_in,
                              void* d_out, int out_size, void* d_ws, size_t ws_size,
                              hipStream_t stream) {
    const float* in    = (const float*)d_in[0];
    const int*   qw    = (const int*)  d_in[1];
    const int*   zp    = (const int*)  d_in[2];
    const float* scale = (const float*)d_in[3];
    const float* bias  = (const float*)d_in[4];
    float*       out   = (float*)d_out;
    float*       sums  = (float*)d_ws;   // 8 floats

    insum_kernel<<<1, 512, 0, stream>>>(in, sums);

    const int groups = OUT_F / 4;        // 2752
    const int blocks = groups / 4;       // 688 blocks x 4 waves
    qlinear_kernel<<<blocks, 256, 0, stream>>>(in, qw, zp, scale, bias, sums, out);
}

// Round 2
// 47.668 us; speedup vs baseline: 1.1827x; 1.1827x over previous
//
#include <hip/hip_runtime.h>

#define OUT_F 11008
#define IN_F  4096
#define BATCH 8
#define NSTEP (IN_F / 256)   // 16 k-steps, 256 k per step (lane*4 each)

// One kernel: 4 output rows per wave, full K per wave, software-pipelined
// loads (depth-1 lookahead, loads for t+1 issued BEFORE FMA(t)).
// zero-point folded out: out = scale*(dot - zp*rowsum(in_b)) + bias,
// rowsum computed in-loop by every wave (input is L2-resident; +32 VALU/step).
__global__ __launch_bounds__(256) void qlinear_kernel(
        const float* __restrict__ in, const int* __restrict__ qw,
        const int* __restrict__ zp, const float* __restrict__ scale,
        const float* __restrict__ bias, float* __restrict__ out) {
    const int wave  = threadIdx.x >> 6;            // 0..3
    const int lane  = threadIdx.x & 63;
    const int group = blockIdx.x * 4 + wave;       // 0..2751
    const int row0  = group * 4;
    const int l4    = lane * 4;

    const int* q0 = qw + (size_t)(row0 + 0) * IN_F + l4;
    const int* q1 = qw + (size_t)(row0 + 1) * IN_F + l4;
    const int* q2 = qw + (size_t)(row0 + 2) * IN_F + l4;
    const int* q3 = qw + (size_t)(row0 + 3) * IN_F + l4;
    const float* x0 = in + l4;

    float acc[4][8];
    float asum[8];
    #pragma unroll
    for (int r = 0; r < 4; ++r)
        #pragma unroll
        for (int b = 0; b < 8; ++b) acc[r][b] = 0.f;
    #pragma unroll
    for (int b = 0; b < 8; ++b) asum[b] = 0.f;

    int4   w[2][4];
    float4 x[2][8];

    // prologue: step 0 into buffer 0 (weights first: longest latency)
    w[0][0] = *reinterpret_cast<const int4*>(q0);
    w[0][1] = *reinterpret_cast<const int4*>(q1);
    w[0][2] = *reinterpret_cast<const int4*>(q2);
    w[0][3] = *reinterpret_cast<const int4*>(q3);
    #pragma unroll
    for (int b = 0; b < 8; ++b)
        x[0][b] = *reinterpret_cast<const float4*>(x0 + b * IN_F);

    #pragma unroll
    for (int t = 0; t < NSTEP; ++t) {
        const int c = t & 1, n = c ^ 1;
        if (t + 1 < NSTEP) {
            const int off = (t + 1) * 256;
            // issue next step's loads BEFORE consuming current buffer
            w[n][0] = *reinterpret_cast<const int4*>(q0 + off);
            w[n][1] = *reinterpret_cast<const int4*>(q1 + off);
            w[n][2] = *reinterpret_cast<const int4*>(q2 + off);
            w[n][3] = *reinterpret_cast<const int4*>(q3 + off);
            #pragma unroll
            for (int b = 0; b < 8; ++b)
                x[n][b] = *reinterpret_cast<const float4*>(x0 + b * IN_F + off);
        }

        float f0x = (float)w[c][0].x, f0y = (float)w[c][0].y, f0z = (float)w[c][0].z, f0w = (float)w[c][0].w;
        float f1x = (float)w[c][1].x, f1y = (float)w[c][1].y, f1z = (float)w[c][1].z, f1w = (float)w[c][1].w;
        float f2x = (float)w[c][2].x, f2y = (float)w[c][2].y, f2z = (float)w[c][2].z, f2w = (float)w[c][2].w;
        float f3x = (float)w[c][3].x, f3y = (float)w[c][3].y, f3z = (float)w[c][3].z, f3w = (float)w[c][3].w;

        #pragma unroll
        for (int b = 0; b < 8; ++b) {
            const float4 xv = x[c][b];
            asum[b]   += (xv.x + xv.y) + (xv.z + xv.w);
            acc[0][b] += f0x * xv.x + f0y * xv.y + f0z * xv.z + f0w * xv.w;
            acc[1][b] += f1x * xv.x + f1y * xv.y + f1z * xv.z + f1w * xv.w;
            acc[2][b] += f2x * xv.x + f2y * xv.y + f2z * xv.z + f2w * xv.w;
            acc[3][b] += f3x * xv.x + f3y * xv.y + f3z * xv.z + f3w * xv.w;
        }
    }

    // --- cross-lane reduce of 32 dot-accumulators (register-halving tree) ---
    // after 5 levels + xor32, lane l (l<32) holds full sum of value index l
    float v[32];
    #pragma unroll
    for (int r = 0; r < 4; ++r)
        #pragma unroll
        for (int b = 0; b < 8; ++b) v[r * 8 + b] = acc[r][b];

    #pragma unroll
    for (int k = 0; k < 5; ++k) {
        const bool hi = (lane >> k) & 1;
        const int  n  = 32 >> k;
        #pragma unroll
        for (int i = 0; i < 32; ++i) {
            if (i < n / 2) {
                float keep = hi ? v[2 * i + 1] : v[2 * i];
                float send = hi ? v[2 * i]     : v[2 * i + 1];
                v[i] = keep + __shfl_xor(send, 1 << k);
            }
        }
    }
    const float total = v[0] + __shfl_xor(v[0], 32);

    // --- reduce the 8 input row-sums: 3 halving levels -> lane holds (lane&7),
    // then combine across remaining lane bits 3,4,5 ---
    float s[8];
    #pragma unroll
    for (int b = 0; b < 8; ++b) s[b] = asum[b];
    #pragma unroll
    for (int k = 0; k < 3; ++k) {
        const bool hi = (lane >> k) & 1;
        const int  n  = 8 >> k;
        #pragma unroll
        for (int i = 0; i < 8; ++i) {
            if (i < n / 2) {
                float keep = hi ? s[2 * i + 1] : s[2 * i];
                float send = hi ? s[2 * i]     : s[2 * i + 1];
                s[i] = keep + __shfl_xor(send, 1 << k);
            }
        }
    }
    float S = s[0];
    S += __shfl_xor(S, 8);
    S += __shfl_xor(S, 16);
    S += __shfl_xor(S, 32);   // S = full rowsum of batch (lane&7)

    if (lane < 32) {
        const int r = lane >> 3;
        const int b = lane & 7;
        const int o = row0 + r;
        const float res = scale[o] * (total - (float)zp[o] * S) + bias[o];
        out[(size_t)b * OUT_F + o] = res;
    }
}

extern "C" void kernel_launch(void* const* d_in, const int* in_sizes, int n_in,
                              void* d_out, int out_size, void* d_ws, size_t ws_size,
                              hipStream_t stream) {
    const float* in    = (const float*)d_in[0];
    const int*   qw    = (const int*)  d_in[1];
    const int*   zp    = (const int*)  d_in[2];
    const float* scale = (const float*)d_in[3];
    const float* bias  = (const float*)d_in[4];
    float*       out   = (float*)d_out;

    const int groups = OUT_F / 4;        // 2752
    const int blocks = groups / 4;       // 688 blocks x 4 waves
    qlinear_kernel<<<blocks, 256, 0, stream>>>(in, qw, zp, scale, bias, out);
}